// Round 12
// baseline (945.271 us; speedup 1.0000x reference)
//
#include <hip/hip_runtime.h>

#define IMG  512
#define TT   112          // output tile (square) per block
#define RH   8            // halo = max steps per round
#define RLW  132          // SoA row stride dwords: s0'[33] s1[32] s2[32] s3'[33] +2 pad
#define PR   130          // phys rows: logical -1..128

__device__ __forceinline__ float mapf(float g) {
    float t = 3.9f * g;
    return t - t * g;     // R*g*(1-g)
}

// SoA col mapping (buffer cols -1..128):
//   col 4j+0 -> off j ; col 4j+1 -> off 33+j ; col 4j+2 -> off 65+j ;
//   col 4j+3 -> off 98+j ; left-ext col -1 -> off 97 ; right-ext col 128 -> off 32.
// Window col 4pj-1+i, i=0..5 -> offsets {97+pj, pj, 33+pj, 65+pj, 98+pj, 1+pj}
// -> lane base (row + pj) + CONSTANT offsets {97,0,33,65,98,1}: compiler CSEs the
// base and merges {97,98},{0,1},{33,65} into ds_read2_b32. Stride-1 across lanes.
#define RD(P, M) do {                       \
    const float* _p = (P);                  \
    (M)[0] = _p[97 + pj];                   \
    (M)[1] = _p[pj];                        \
    (M)[2] = _p[33 + pj];                   \
    (M)[3] = _p[65 + pj];                   \
    (M)[4] = _p[98 + pj];                   \
    (M)[5] = _p[1 + pj];                    \
} while (0)

// One temporal round: init M=map(src), run `steps` CML steps, store grid to
// dst (clipped if do_clip). 112x112 tile, buffer 128x128 (halo 8):
// redundancy 1.35x (vs 1.72x at 48x112). 1024 threads, each owns a 4-wide x
// 4-tall patch. 68.6 KB LDS -> 2 blocks/CU; ~52 live VGPRs fits the 64
// budget at 8 waves/SIMD (no spills).
__global__ __launch_bounds__(1024) void cml_round(
    const float* __restrict__ src,
    const float* __restrict__ drv,
    const float* __restrict__ Kw,
    float* __restrict__ dst,
    int steps, int do_clip)
{
    __shared__ float B[PR * RLW];      // 68.6 KiB

    const int tid = threadIdx.x;
    const int bid = blockIdx.x;
    const int bc  = bid / 25;               // image*channel index
    const int tl  = bid % 25;               // 5x5 tiles of 112
    const int gy0 = (tl / 5) * TT - RH;     // logical buffer row 0 -> gy0
    const int gx0 = (tl % 5) * TT - RH;     // multiple of 4
    const float* __restrict__ simg = src + (size_t)bc * (IMG*IMG);
    const float* __restrict__ dimg = drv + (size_t)bc * (IMG*IMG);
    float*       __restrict__ oimg = dst + (size_t)bc * (IMG*IMG);

    // Folded 3x3 kernel: K' = (0.85*0.3)*K + (0.85*0.7)*delta_center (uniform)
    float kk[9];
    {
        const float c2 = 0.85f * 0.3f;
        const float* kp = Kw + (bc & 3) * 9;
#pragma unroll
        for (int q = 0; q < 9; q++) kk[q] = c2 * kp[q];
        kk[4] += 0.85f * 0.7f;
    }

    const int pj  = tid & 31;               // col patch: owned cols 4pj..4pj+3
    const int pi  = tid >> 5;               // row band:  owned rows 4pi..4pi+3
    const int y0  = pi * 4;
    const int gxb = gx0 + pj * 4;           // global col of owned float4
    const float fxc = ((unsigned)gxb < IMG) ? 1.0f : 0.0f;

    // per-row combined boundary flags, hoisted (row-flag * col-flag)
    float ffr[4];
#pragma unroll
    for (int rr = 0; rr < 4; rr++)
        ffr[rr] = (((unsigned)(gy0 + y0 + rr) < IMG) ? 1.0f : 0.0f) * fxc;

    // beta*drive for owned cells, hoisted to registers (zero per-step cost)
    float dvs[16];
#pragma unroll
    for (int rr = 0; rr < 4; rr++) {
        const int gy = gy0 + y0 + rr;
        float4 dv = make_float4(0.f, 0.f, 0.f, 0.f);
        if ((unsigned)gy < IMG && (unsigned)gxb < IMG)
            dv = *(const float4*)(dimg + gy*IMG + gxb);
        dvs[rr*4+0] = 0.15f * dv.x;
        dvs[rr*4+1] = 0.15f * dv.y;
        dvs[rr*4+2] = 0.15f * dv.z;
        dvs[rr*4+3] = 0.15f * dv.w;
    }

    // Init: B = map(src) over phys rows 0..129 (logical -1..128), SoA layout.
    for (int u = tid; u < PR * 32; u += 1024) {
        const int r = u >> 5;
        const int p = u & 31;
        const int gy  = gy0 + r - 1;
        const int gxq = gx0 + p * 4;
        const bool rowok = (unsigned)gy < IMG;
        float4 v = make_float4(0.f, 0.f, 0.f, 0.f);
        if (rowok && (unsigned)gxq < IMG)
            v = *(const float4*)(simg + gy*IMG + gxq);   // gxq<=508: no row cross
        float* row = B + r * RLW;
        row[p]      = mapf(v.x);
        row[33 + p] = mapf(v.y);
        row[65 + p] = mapf(v.z);
        row[98 + p] = mapf(v.w);
        if (p == 0) {                        // left-ext col -1 -> off 97
            float e = (rowok && (unsigned)(gx0 - 1) < IMG)
                    ? simg[gy*IMG + gx0 - 1] : 0.f;
            row[97] = mapf(e);
        }
        if (p == 31) {                       // right-ext col 128 -> off 32
            float e = (rowok && (unsigned)(gx0 + 128) < IMG)
                    ? simg[gy*IMG + gx0 + 128] : 0.f;
            row[32] = mapf(e);
        }
    }
    __syncthreads();

    float st[16];
#pragma unroll 1
    for (int step = 0; step < steps - 1; step++) {
        {
            float a[6], b6[6], c6[6];
            const float* p = B + y0 * RLW;      // phys y0 = logical y0-1
            RD(p, a);  p += RLW;
            RD(p, b6);
#pragma unroll
            for (int rr = 0; rr < 4; rr++) {
                p += RLW;
                RD(p, c6);
                const float ff = ffr[rr];
#pragma unroll
                for (int k = 0; k < 4; k++) {
                    float s = dvs[rr*4+k];
                    s += kk[0]*a[k]  + kk[1]*a[k+1]  + kk[2]*a[k+2];
                    s += kk[3]*b6[k] + kk[4]*b6[k+1] + kk[5]*b6[k+2];
                    s += kk[6]*c6[k] + kk[7]*c6[k+1] + kk[8]*c6[k+2];
                    const float t = 3.9f * s;
                    st[rr*4+k] = (t - t*s) * ff;
                }
#pragma unroll
                for (int q = 0; q < 6; q++) { a[q] = b6[q]; b6[q] = c6[q]; }
            }
        }
        __syncthreads();   // all reads done before any write (WAR)
#pragma unroll
        for (int rr = 0; rr < 4; rr++) {
            float* w = B + (y0 + 1 + rr) * RLW;    // phys = logical+1
            w[pj]      = st[rr*4+0];
            w[33 + pj] = st[rr*4+1];
            w[65 + pj] = st[rr*4+2];
            w[98 + pj] = st[rr*4+3];
        }
        __syncthreads();   // writes done before next step's reads (RAW)
    }

    // Final step of the round: compute grid (no map), store valid interior.
    {
        float a[6], b6[6], c6[6];
        const float* p = B + y0 * RLW;
        RD(p, a);  p += RLW;
        RD(p, b6);
#pragma unroll
        for (int rr = 0; rr < 4; rr++) {
            p += RLW;
            RD(p, c6);
#pragma unroll
            for (int k = 0; k < 4; k++) {
                float s = dvs[rr*4+k];
                s += kk[0]*a[k]  + kk[1]*a[k+1]  + kk[2]*a[k+2];
                s += kk[3]*b6[k] + kk[4]*b6[k+1] + kk[5]*b6[k+2];
                s += kk[6]*c6[k] + kk[7]*c6[k+1] + kk[8]*c6[k+2];
                st[rr*4+k] = s;
            }
#pragma unroll
            for (int q = 0; q < 6; q++) { a[q] = b6[q]; b6[q] = c6[q]; }
        }
    }
    // Valid region: rows/cols [8,120) -> pi,pj in [2,29].
    if (pi >= 2 && pi <= 29 && pj >= 2 && pj <= 29) {
#pragma unroll
        for (int rr = 0; rr < 4; rr++) {
            const int gy = gy0 + y0 + rr;       // >= 0 (pi>=2, gy0>=-8)
            if (gy < IMG && gxb + 3 < IMG) {    // gxb >= 0 (pj>=2)
                float4 v = make_float4(st[rr*4+0], st[rr*4+1],
                                       st[rr*4+2], st[rr*4+3]);
                if (do_clip) {
                    v.x = fminf(fmaxf(v.x, 1e-4f), 1.0f - 1e-4f);
                    v.y = fminf(fmaxf(v.y, 1e-4f), 1.0f - 1e-4f);
                    v.z = fminf(fmaxf(v.z, 1e-4f), 1.0f - 1e-4f);
                    v.w = fminf(fmaxf(v.w, 1e-4f), 1.0f - 1e-4f);
                }
                *(float4*)(oimg + gy*IMG + gxb) = v;
            }
        }
    }
}

// ---------------- Fallback: single-kernel 15-step version (Round-4) ----------
#define TILE  128
#define OFF_Y 16
#define OFF_X 18
#define BUFY  160
#define BUFX  164
#define LW    172
#define NP    1014

__device__ __forceinline__ void read_row6(const float* __restrict__ p, int xw,
                                          float* m) {
    const float4 mid = *(const float4*)(p + xw + 4);
    m[0] = p[xw + 3];
    m[1] = mid.x; m[2] = mid.y; m[3] = mid.z; m[4] = mid.w;
    m[5] = p[xw + 8];
}

__global__ __launch_bounds__(1024, 4) void cml_fused(
    const float* __restrict__ drive,
    const float* __restrict__ Kw,
    float* __restrict__ out)
{
    __shared__ float lds[BUFY * LW];
    const int tid = threadIdx.x;
    const int bid = blockIdx.x;
    const int bc  = bid >> 4;
    const int tl  = bid & 15;
    const int gy0 = (tl >> 2) * TILE - OFF_Y;
    const int gx0 = (tl & 3)  * TILE - OFF_X;
    const float* __restrict__ img  = drive + (size_t)bc * (IMG*IMG);
    float*       __restrict__ oimg = out   + (size_t)bc * (IMG*IMG);
    float kk[9];
    {
        const float c2 = 0.85f * 0.3f;
        const float* kp = Kw + (bc & 3) * 9;
#pragma unroll
        for (int q = 0; q < 9; q++) kk[q] = c2 * kp[q];
        kk[4] += 0.85f * 0.7f;
    }
    const int t2 = tid < NP ? tid : NP - 1;
    const int pi = t2 / 39;
    const int pj = t2 - pi * 39;
    const int y0 = 2 + 6 * pi;
    const int xw = 4 * pj;
    float dvs[24], fx[4], fy[6];
#pragma unroll
    for (int k = 0; k < 4; k++)
        fx[k] = ((unsigned)(gx0 + xw + 4 + k) < IMG) ? 1.0f : 0.0f;
#pragma unroll
    for (int rr = 0; rr < 6; rr++) {
        const int gy = gy0 + y0 + rr;
        fy[rr] = ((unsigned)gy < IMG) ? 1.0f : 0.0f;
#pragma unroll
        for (int k = 0; k < 4; k++) {
            const int gx = gx0 + xw + 4 + k;
            dvs[rr*4+k] = (((unsigned)gy < IMG) && ((unsigned)gx < IMG))
                        ? 0.15f * img[gy*IMG + gx] : 0.0f;
        }
    }
    for (int u = tid; u < BUFY * (LW/2); u += 1024) {
        const int yy = u / (LW/2);
        const int xx = (u - yy * (LW/2)) * 2;
        const int gy = gy0 + yy;
        const int gxb = gx0 + xx;
        float2 v = make_float2(0.f, 0.f);
        if (xx < BUFX && (unsigned)gy < IMG && (unsigned)gxb < IMG)
            v = *(const float2*)(img + gy*IMG + gxb);
        v.x = mapf(v.x); v.y = mapf(v.y);
        *(float2*)(lds + yy*LW + xx) = v;
    }
    __syncthreads();
    float st[24];
#pragma unroll 1
    for (int step = 0; step < 14; step++) {
        {
            float a[6], b[6], c[6];
            const float* p = lds + (y0 - 1) * LW;
            read_row6(p, xw, a);  p += LW;
            read_row6(p, xw, b);
#pragma unroll
            for (int rr = 0; rr < 6; rr++) {
                p += LW;
                read_row6(p, xw, c);
                const float fyr = fy[rr];
#pragma unroll
                for (int k = 0; k < 4; k++) {
                    float s = dvs[rr*4+k];
                    s += kk[0]*a[k] + kk[1]*a[k+1] + kk[2]*a[k+2];
                    s += kk[3]*b[k] + kk[4]*b[k+1] + kk[5]*b[k+2];
                    s += kk[6]*c[k] + kk[7]*c[k+1] + kk[8]*c[k+2];
                    const float t = 3.9f * s;
                    st[rr*4+k] = (t - t*s) * fyr * fx[k];
                }
#pragma unroll
                for (int q = 0; q < 6; q++) { a[q] = b[q]; b[q] = c[q]; }
            }
        }
        __syncthreads();
        {
            float* w = lds + y0 * LW + xw + 4;
#pragma unroll
            for (int rr = 0; rr < 6; rr++) {
                *(float4*)w = make_float4(st[rr*4+0], st[rr*4+1],
                                          st[rr*4+2], st[rr*4+3]);
                w += LW;
            }
        }
        __syncthreads();
    }
    {
        float a[6], b[6], c[6];
        const float* p = lds + (y0 - 1) * LW;
        read_row6(p, xw, a);  p += LW;
        read_row6(p, xw, b);
#pragma unroll
        for (int rr = 0; rr < 6; rr++) {
            p += LW;
            read_row6(p, xw, c);
#pragma unroll
            for (int k = 0; k < 4; k++) {
                float s = dvs[rr*4+k];
                s += kk[0]*a[k] + kk[1]*a[k+1] + kk[2]*a[k+2];
                s += kk[3]*b[k] + kk[4]*b[k+1] + kk[5]*b[k+2];
                s += kk[6]*c[k] + kk[7]*c[k+1] + kk[8]*c[k+2];
                st[rr*4+k] = fminf(fmaxf(s, 1e-4f), 1.0f - 1e-4f);
            }
#pragma unroll
            for (int q = 0; q < 6; q++) { a[q] = b[q]; b[q] = c[q]; }
        }
    }
#pragma unroll
    for (int rr = 0; rr < 6; rr++) {
        const int r = y0 + rr;
        if (r >= OFF_Y && r < OFF_Y + TILE) {
#pragma unroll
            for (int h = 0; h < 2; h++) {
                const int col = xw + 4 + 2*h;
                if (col >= OFF_X && col + 1 < OFF_X + TILE) {
                    *(float2*)(oimg + (size_t)(gy0 + r) * IMG + (gx0 + col)) =
                        make_float2(st[rr*4 + 2*h], st[rr*4 + 2*h + 1]);
                }
            }
        }
    }
}

extern "C" void kernel_launch(void* const* d_in, const int* in_sizes, int n_in,
                              void* d_out, int out_size, void* d_ws, size_t ws_size,
                              hipStream_t stream)
{
    const float* drive = (const float*)d_in[0];
    const float* Kw    = (const float*)d_in[1];
    float* out         = (float*)d_out;
    const size_t need  = (size_t)256 * IMG * IMG * sizeof(float);  // 256 MiB

    if (ws_size >= need) {
        float* g8 = (float*)d_ws;
        // 256 images x 25 tiles (5x5 of 112) = 6400 blocks, 1024 threads
        cml_round<<<dim3(6400), dim3(1024), 0, stream>>>(drive, drive, Kw, g8, 8, 0);
        cml_round<<<dim3(6400), dim3(1024), 0, stream>>>(g8, drive, Kw, out, 7, 1);
    } else {
        cml_fused<<<dim3(4096), dim3(1024), 0, stream>>>(drive, Kw, out);
    }
}

// Round 13
// 845.920 us; speedup vs baseline: 1.1174x; 1.1174x over previous
//
#include <hip/hip_runtime.h>

#define IMG  512
#define TR   48           // output tile rows per block
#define TC   112          // output tile cols per block
#define RH   8            // halo = max steps per round
#define RLW  132          // SoA row stride dwords: s0'[33] s1[32] s2[32] s3'[33] +2 pad
#define PR   66           // phys rows: logical -1..64

typedef float v2 __attribute__((ext_vector_type(2)));

__device__ __forceinline__ float mapf(float g) {
    float t = 3.9f * g;
    return t - t * g;     // R*g*(1-g)
}

// Vertical row-pair load: one ds_read2_b32 (offset0=O, offset1=O+132), lands
// in a VGPR pair used directly as <2 x float>. O must be a literal.
#define LD2(P, O) ({ v2 _r; _r.x = (P)[(O)]; _r.y = (P)[(O) + RLW]; _r; })

// SoA col mapping (buffer cols -1..128):
//   col 4j+0 -> off j ; col 4j+1 -> off 33+j ; col 4j+2 -> off 65+j ;
//   col 4j+3 -> off 98+j ; left-ext col -1 -> off 97 ; right-ext col 128 -> off 32.
// Per-lane base includes pj; window col offsets are the literals
// {97,0,33,65,98,1} (window cols 4pj-1 .. 4pj+4).

// One temporal round: init M=map(src), run `steps` CML steps, store grid to
// dst (clipped if do_clip). R10 geometry (512 thr, 4x4 patch, 34.8 KB LDS ->
// 4 blocks/CU) + packed <2 x float> math: each thread computes its 4 rows as
// TWO ROW-PAIRS; operands load as vertical ds_read2 pairs (constant offsets),
// conv drops 144 fma -> 72 v_pk_fma_f32 at identical LDS traffic.
__global__ __launch_bounds__(512) void cml_round(
    const float* __restrict__ src,
    const float* __restrict__ drv,
    const float* __restrict__ Kw,
    float* __restrict__ dst,
    int steps, int do_clip)
{
    __shared__ float B[PR * RLW];      // 34.8 KiB

    const int tid = threadIdx.x;
    const int bid = blockIdx.x;
    const int bc  = bid / 55;               // image*channel index
    const int tl  = bid % 55;               // 11 row-strips x 5 col-tiles
    const int gy0 = (tl / 5) * TR - RH;     // logical buffer row 0 -> gy0
    const int gx0 = (tl % 5) * TC - RH;     // multiple of 4
    const float* __restrict__ simg = src + (size_t)bc * (IMG*IMG);
    const float* __restrict__ dimg = drv + (size_t)bc * (IMG*IMG);
    float*       __restrict__ oimg = dst + (size_t)bc * (IMG*IMG);

    // Folded 3x3 kernel: K' = (0.85*0.3)*K + (0.85*0.7)*delta_center.
    // Block-uniform -> SGPRs (1 SGPR operand per pk op is legal).
    float kk[9];
    {
        const float c2 = 0.85f * 0.3f;
        const float* kp = Kw + (bc & 3) * 9;
#pragma unroll
        for (int q = 0; q < 9; q++) kk[q] = c2 * kp[q];
        kk[4] += 0.85f * 0.7f;
    }

    const int pj  = tid & 31;               // col patch: owned cols 4pj..4pj+3
    const int pi  = tid >> 5;               // row band:  owned rows 4pi..4pi+3
    const int y0  = pi * 4;
    const int gxb = gx0 + pj * 4;           // global col of owned float4
    const float fxc = ((unsigned)gxb < IMG) ? 1.0f : 0.0f;

    // boundary flag pairs for rows {r0,r0+1} and {r0+2,r0+3}
    v2 fp1, fp2;
    fp1.x = (((unsigned)(gy0 + y0 + 0) < IMG) ? 1.0f : 0.0f) * fxc;
    fp1.y = (((unsigned)(gy0 + y0 + 1) < IMG) ? 1.0f : 0.0f) * fxc;
    fp2.x = (((unsigned)(gy0 + y0 + 2) < IMG) ? 1.0f : 0.0f) * fxc;
    fp2.y = (((unsigned)(gy0 + y0 + 3) < IMG) ? 1.0f : 0.0f) * fxc;

    // beta*drive pre-paired across rows: dp1[k]={r0,r0+1}, dp2[k]={r0+2,r0+3}
    v2 dp1[4], dp2[4];
    {
        float4 dr[4];
#pragma unroll
        for (int rr = 0; rr < 4; rr++) {
            const int gy = gy0 + y0 + rr;
            float4 dv = make_float4(0.f, 0.f, 0.f, 0.f);
            if ((unsigned)gy < IMG && (unsigned)gxb < IMG)
                dv = *(const float4*)(dimg + gy*IMG + gxb);
            dr[rr] = dv;
        }
        dp1[0] = v2{0.15f*dr[0].x, 0.15f*dr[1].x};
        dp1[1] = v2{0.15f*dr[0].y, 0.15f*dr[1].y};
        dp1[2] = v2{0.15f*dr[0].z, 0.15f*dr[1].z};
        dp1[3] = v2{0.15f*dr[0].w, 0.15f*dr[1].w};
        dp2[0] = v2{0.15f*dr[2].x, 0.15f*dr[3].x};
        dp2[1] = v2{0.15f*dr[2].y, 0.15f*dr[3].y};
        dp2[2] = v2{0.15f*dr[2].z, 0.15f*dr[3].z};
        dp2[3] = v2{0.15f*dr[2].w, 0.15f*dr[3].w};
    }

    // Init: B = map(src) over phys rows 0..65 (logical -1..64), SoA layout.
    for (int u = tid; u < PR * 32; u += 512) {
        const int r = u >> 5;
        const int p = u & 31;
        const int gy  = gy0 + r - 1;
        const int gxq = gx0 + p * 4;
        const bool rowok = (unsigned)gy < IMG;
        float4 v = make_float4(0.f, 0.f, 0.f, 0.f);
        if (rowok && (unsigned)gxq < IMG)
            v = *(const float4*)(simg + gy*IMG + gxq);   // gxq<=508: no row cross
        float* row = B + r * RLW;
        row[p]      = mapf(v.x);
        row[33 + p] = mapf(v.y);
        row[65 + p] = mapf(v.z);
        row[98 + p] = mapf(v.w);
        if (p == 0) {                        // left-ext col -1 -> off 97
            float e = (rowok && (unsigned)(gx0 - 1) < IMG)
                    ? simg[gy*IMG + gx0 - 1] : 0.f;
            row[97] = mapf(e);
        }
        if (p == 31) {                       // right-ext col 128 -> off 32
            float e = (rowok && (unsigned)(gx0 + 128) < IMG)
                    ? simg[gy*IMG + gx0 + 128] : 0.f;
            row[32] = mapf(e);
        }
    }
    __syncthreads();

    v2 s1[4], s2[4];
#pragma unroll 1
    for (int step = 0; step < steps - 1; step++) {
        {
            // per-lane bases: phys rows y0 (=logical r0-1), y0+2, y0+4
            const float* p0 = B + y0 * RLW + pj;
            const float* p2 = p0 + 2 * RLW;
            const float* p4 = p0 + 4 * RLW;

            // T = rows {r0-1, r0}; Bo = rows {r0+1, r0+2}  (window cols w0..w5)
            v2 T0 = LD2(p0, 97), T1 = LD2(p0, 0), T2 = LD2(p0, 33),
               T3 = LD2(p0, 65), T4 = LD2(p0, 98), T5 = LD2(p0, 1);
            v2 Bo0 = LD2(p2, 97), Bo1 = LD2(p2, 0), Bo2 = LD2(p2, 33),
               Bo3 = LD2(p2, 65), Bo4 = LD2(p2, 98), Bo5 = LD2(p2, 1);
            // M1 = rows {r0, r0+1}
            v2 M10 = v2{T0.y, Bo0.x}, M11 = v2{T1.y, Bo1.x},
               M12 = v2{T2.y, Bo2.x}, M13 = v2{T3.y, Bo3.x},
               M14 = v2{T4.y, Bo4.x}, M15 = v2{T5.y, Bo5.x};
            // window order: cols 4pj-1,4pj,4pj+1,4pj+2,4pj+3,4pj+4
            //   = offsets {97,0,33,65,98,1} -> indices 0..5 below
            {
                const v2 Ta[6]  = {T0, T1, T2, T3, T4, T5};
                const v2 Ma[6]  = {M10, M11, M12, M13, M14, M15};
                const v2 Ba[6]  = {Bo0, Bo1, Bo2, Bo3, Bo4, Bo5};
#pragma unroll
                for (int k = 0; k < 4; k++) {
                    v2 s = dp1[k];
                    s += kk[0]*Ta[k] + kk[1]*Ta[k+1] + kk[2]*Ta[k+2];
                    s += kk[3]*Ma[k] + kk[4]*Ma[k+1] + kk[5]*Ma[k+2];
                    s += kk[6]*Ba[k] + kk[7]*Ba[k+1] + kk[8]*Ba[k+2];
                    v2 t = 3.9f * s;
                    s1[k] = (t - t*s) * fp1;
                }
            }
            // B2 = rows {r0+3, r0+4}; M2 = rows {r0+2, r0+3}
            v2 B20 = LD2(p4, 97), B21 = LD2(p4, 0), B22 = LD2(p4, 33),
               B23 = LD2(p4, 65), B24 = LD2(p4, 98), B25 = LD2(p4, 1);
            v2 M20 = v2{Bo0.y, B20.x}, M21 = v2{Bo1.y, B21.x},
               M22 = v2{Bo2.y, B22.x}, M23 = v2{Bo3.y, B23.x},
               M24 = v2{Bo4.y, B24.x}, M25 = v2{Bo5.y, B25.x};
            {
                const v2 Ta[6]  = {Bo0, Bo1, Bo2, Bo3, Bo4, Bo5};
                const v2 Ma[6]  = {M20, M21, M22, M23, M24, M25};
                const v2 Ba[6]  = {B20, B21, B22, B23, B24, B25};
#pragma unroll
                for (int k = 0; k < 4; k++) {
                    v2 s = dp2[k];
                    s += kk[0]*Ta[k] + kk[1]*Ta[k+1] + kk[2]*Ta[k+2];
                    s += kk[3]*Ma[k] + kk[4]*Ma[k+1] + kk[5]*Ma[k+2];
                    s += kk[6]*Ba[k] + kk[7]*Ba[k+1] + kk[8]*Ba[k+2];
                    v2 t = 3.9f * s;
                    s2[k] = (t - t*s) * fp2;
                }
            }
        }
        __syncthreads();   // all reads done before any write (WAR)
        {
            // rows r0..r0+3 -> phys y0+1..y0+4; vertical ds_write2 pairs
            float* w0 = B + (y0 + 1) * RLW + pj;
            float* w2 = w0 + 2 * RLW;
            w0[0]        = s1[0].x;  w0[RLW]        = s1[0].y;
            w0[33]       = s1[1].x;  w0[33 + RLW]   = s1[1].y;
            w0[65]       = s1[2].x;  w0[65 + RLW]   = s1[2].y;
            w0[98]       = s1[3].x;  w0[98 + RLW]   = s1[3].y;
            w2[0]        = s2[0].x;  w2[RLW]        = s2[0].y;
            w2[33]       = s2[1].x;  w2[33 + RLW]   = s2[1].y;
            w2[65]       = s2[2].x;  w2[65 + RLW]   = s2[2].y;
            w2[98]       = s2[3].x;  w2[98 + RLW]   = s2[3].y;
        }
        __syncthreads();   // writes done before next step's reads (RAW)
    }

    // Final step of the round: compute grid (no map/flag), store interior.
    {
        const float* p0 = B + y0 * RLW + pj;
        const float* p2 = p0 + 2 * RLW;
        const float* p4 = p0 + 4 * RLW;
        v2 T0 = LD2(p0, 97), T1 = LD2(p0, 0), T2 = LD2(p0, 33),
           T3 = LD2(p0, 65), T4 = LD2(p0, 98), T5 = LD2(p0, 1);
        v2 Bo0 = LD2(p2, 97), Bo1 = LD2(p2, 0), Bo2 = LD2(p2, 33),
           Bo3 = LD2(p2, 65), Bo4 = LD2(p2, 98), Bo5 = LD2(p2, 1);
        v2 M10 = v2{T0.y, Bo0.x}, M11 = v2{T1.y, Bo1.x},
           M12 = v2{T2.y, Bo2.x}, M13 = v2{T3.y, Bo3.x},
           M14 = v2{T4.y, Bo4.x}, M15 = v2{T5.y, Bo5.x};
        {
            const v2 Ta[6]  = {T0, T1, T2, T3, T4, T5};
            const v2 Ma[6]  = {M10, M11, M12, M13, M14, M15};
            const v2 Ba[6]  = {Bo0, Bo1, Bo2, Bo3, Bo4, Bo5};
#pragma unroll
            for (int k = 0; k < 4; k++) {
                v2 s = dp1[k];
                s += kk[0]*Ta[k] + kk[1]*Ta[k+1] + kk[2]*Ta[k+2];
                s += kk[3]*Ma[k] + kk[4]*Ma[k+1] + kk[5]*Ma[k+2];
                s += kk[6]*Ba[k] + kk[7]*Ba[k+1] + kk[8]*Ba[k+2];
                s1[k] = s;
            }
        }
        v2 B20 = LD2(p4, 97), B21 = LD2(p4, 0), B22 = LD2(p4, 33),
           B23 = LD2(p4, 65), B24 = LD2(p4, 98), B25 = LD2(p4, 1);
        v2 M20 = v2{Bo0.y, B20.x}, M21 = v2{Bo1.y, B21.x},
           M22 = v2{Bo2.y, B22.x}, M23 = v2{Bo3.y, B23.x},
           M24 = v2{Bo4.y, B24.x}, M25 = v2{Bo5.y, B25.x};
        {
            const v2 Ta[6]  = {Bo0, Bo1, Bo2, Bo3, Bo4, Bo5};
            const v2 Ma[6]  = {M20, M21, M22, M23, M24, M25};
            const v2 Ba[6]  = {B20, B21, B22, B23, B24, B25};
#pragma unroll
            for (int k = 0; k < 4; k++) {
                v2 s = dp2[k];
                s += kk[0]*Ta[k] + kk[1]*Ta[k+1] + kk[2]*Ta[k+2];
                s += kk[3]*Ma[k] + kk[4]*Ma[k+1] + kk[5]*Ma[k+2];
                s += kk[6]*Ba[k] + kk[7]*Ba[k+1] + kk[8]*Ba[k+2];
                s2[k] = s;
            }
        }
    }
    // Valid region: rows [8,56) -> pi in [2,13]; cols [8,120) -> pj in [2,29].
    if (pi >= 2 && pi <= 13 && pj >= 2 && pj <= 29) {
        float rowv[4][4];
#pragma unroll
        for (int k = 0; k < 4; k++) {
            rowv[0][k] = s1[k].x;  rowv[1][k] = s1[k].y;
            rowv[2][k] = s2[k].x;  rowv[3][k] = s2[k].y;
        }
#pragma unroll
        for (int rr = 0; rr < 4; rr++) {
            const int gy = gy0 + y0 + rr;       // >= 0 (pi>=2)
            if (gy < IMG && gxb + 3 < IMG) {
                float4 v = make_float4(rowv[rr][0], rowv[rr][1],
                                       rowv[rr][2], rowv[rr][3]);
                if (do_clip) {
                    v.x = fminf(fmaxf(v.x, 1e-4f), 1.0f - 1e-4f);
                    v.y = fminf(fmaxf(v.y, 1e-4f), 1.0f - 1e-4f);
                    v.z = fminf(fmaxf(v.z, 1e-4f), 1.0f - 1e-4f);
                    v.w = fminf(fmaxf(v.w, 1e-4f), 1.0f - 1e-4f);
                }
                *(float4*)(oimg + gy*IMG + gxb) = v;
            }
        }
    }
}

// ---------------- Fallback: single-kernel 15-step version (Round-4) ----------
#define TILE  128
#define OFF_Y 16
#define OFF_X 18
#define BUFY  160
#define BUFX  164
#define LW    172
#define NP    1014

__device__ __forceinline__ void read_row6(const float* __restrict__ p, int xw,
                                          float* m) {
    const float4 mid = *(const float4*)(p + xw + 4);
    m[0] = p[xw + 3];
    m[1] = mid.x; m[2] = mid.y; m[3] = mid.z; m[4] = mid.w;
    m[5] = p[xw + 8];
}

__global__ __launch_bounds__(1024, 4) void cml_fused(
    const float* __restrict__ drive,
    const float* __restrict__ Kw,
    float* __restrict__ out)
{
    __shared__ float lds[BUFY * LW];
    const int tid = threadIdx.x;
    const int bid = blockIdx.x;
    const int bc  = bid >> 4;
    const int tl  = bid & 15;
    const int gy0 = (tl >> 2) * TILE - OFF_Y;
    const int gx0 = (tl & 3)  * TILE - OFF_X;
    const float* __restrict__ img  = drive + (size_t)bc * (IMG*IMG);
    float*       __restrict__ oimg = out   + (size_t)bc * (IMG*IMG);
    float kk[9];
    {
        const float c2 = 0.85f * 0.3f;
        const float* kp = Kw + (bc & 3) * 9;
#pragma unroll
        for (int q = 0; q < 9; q++) kk[q] = c2 * kp[q];
        kk[4] += 0.85f * 0.7f;
    }
    const int t2 = tid < NP ? tid : NP - 1;
    const int pi = t2 / 39;
    const int pj = t2 - pi * 39;
    const int y0 = 2 + 6 * pi;
    const int xw = 4 * pj;
    float dvs[24], fx[4], fy[6];
#pragma unroll
    for (int k = 0; k < 4; k++)
        fx[k] = ((unsigned)(gx0 + xw + 4 + k) < IMG) ? 1.0f : 0.0f;
#pragma unroll
    for (int rr = 0; rr < 6; rr++) {
        const int gy = gy0 + y0 + rr;
        fy[rr] = ((unsigned)gy < IMG) ? 1.0f : 0.0f;
#pragma unroll
        for (int k = 0; k < 4; k++) {
            const int gx = gx0 + xw + 4 + k;
            dvs[rr*4+k] = (((unsigned)gy < IMG) && ((unsigned)gx < IMG))
                        ? 0.15f * img[gy*IMG + gx] : 0.0f;
        }
    }
    for (int u = tid; u < BUFY * (LW/2); u += 1024) {
        const int yy = u / (LW/2);
        const int xx = (u - yy * (LW/2)) * 2;
        const int gy = gy0 + yy;
        const int gxb = gx0 + xx;
        float2 v = make_float2(0.f, 0.f);
        if (xx < BUFX && (unsigned)gy < IMG && (unsigned)gxb < IMG)
            v = *(const float2*)(img + gy*IMG + gxb);
        v.x = mapf(v.x); v.y = mapf(v.y);
        *(float2*)(lds + yy*LW + xx) = v;
    }
    __syncthreads();
    float st[24];
#pragma unroll 1
    for (int step = 0; step < 14; step++) {
        {
            float a[6], b[6], c[6];
            const float* p = lds + (y0 - 1) * LW;
            read_row6(p, xw, a);  p += LW;
            read_row6(p, xw, b);
#pragma unroll
            for (int rr = 0; rr < 6; rr++) {
                p += LW;
                read_row6(p, xw, c);
                const float fyr = fy[rr];
#pragma unroll
                for (int k = 0; k < 4; k++) {
                    float s = dvs[rr*4+k];
                    s += kk[0]*a[k] + kk[1]*a[k+1] + kk[2]*a[k+2];
                    s += kk[3]*b[k] + kk[4]*b[k+1] + kk[5]*b[k+2];
                    s += kk[6]*c[k] + kk[7]*c[k+1] + kk[8]*c[k+2];
                    const float t = 3.9f * s;
                    st[rr*4+k] = (t - t*s) * fyr * fx[k];
                }
#pragma unroll
                for (int q = 0; q < 6; q++) { a[q] = b[q]; b[q] = c[q]; }
            }
        }
        __syncthreads();
        {
            float* w = lds + y0 * LW + xw + 4;
#pragma unroll
            for (int rr = 0; rr < 6; rr++) {
                *(float4*)w = make_float4(st[rr*4+0], st[rr*4+1],
                                          st[rr*4+2], st[rr*4+3]);
                w += LW;
            }
        }
        __syncthreads();
    }
    {
        float a[6], b[6], c[6];
        const float* p = lds + (y0 - 1) * LW;
        read_row6(p, xw, a);  p += LW;
        read_row6(p, xw, b);
#pragma unroll
        for (int rr = 0; rr < 6; rr++) {
            p += LW;
            read_row6(p, xw, c);
#pragma unroll
            for (int k = 0; k < 4; k++) {
                float s = dvs[rr*4+k];
                s += kk[0]*a[k] + kk[1]*a[k+1] + kk[2]*a[k+2];
                s += kk[3]*b[k] + kk[4]*b[k+1] + kk[5]*b[k+2];
                s += kk[6]*c[k] + kk[7]*c[k+1] + kk[8]*c[k+2];
                st[rr*4+k] = fminf(fmaxf(s, 1e-4f), 1.0f - 1e-4f);
            }
#pragma unroll
            for (int q = 0; q < 6; q++) { a[q] = b[q]; b[q] = c[q]; }
        }
    }
#pragma unroll
    for (int rr = 0; rr < 6; rr++) {
        const int r = y0 + rr;
        if (r >= OFF_Y && r < OFF_Y + TILE) {
#pragma unroll
            for (int h = 0; h < 2; h++) {
                const int col = xw + 4 + 2*h;
                if (col >= OFF_X && col + 1 < OFF_X + TILE) {
                    *(float2*)(oimg + (size_t)(gy0 + r) * IMG + (gx0 + col)) =
                        make_float2(st[rr*4 + 2*h], st[rr*4 + 2*h + 1]);
                }
            }
        }
    }
}

extern "C" void kernel_launch(void* const* d_in, const int* in_sizes, int n_in,
                              void* d_out, int out_size, void* d_ws, size_t ws_size,
                              hipStream_t stream)
{
    const float* drive = (const float*)d_in[0];
    const float* Kw    = (const float*)d_in[1];
    float* out         = (float*)d_out;
    const size_t need  = (size_t)256 * IMG * IMG * sizeof(float);  // 256 MiB

    if (ws_size >= need) {
        float* g8 = (float*)d_ws;
        // 256 images x 55 tiles (11 row-strips x 5 col-tiles) = 14080 blocks
        cml_round<<<dim3(14080), dim3(512), 0, stream>>>(drive, drive, Kw, g8, 8, 0);
        cml_round<<<dim3(14080), dim3(512), 0, stream>>>(g8, drive, Kw, out, 7, 1);
    } else {
        cml_fused<<<dim3(4096), dim3(1024), 0, stream>>>(drive, Kw, out);
    }
}

// Round 14
// 838.051 us; speedup vs baseline: 1.1279x; 1.0094x over previous
//
#include <hip/hip_runtime.h>

#define IMG  512
#define TR   48           // output tile rows per block
#define TC   112          // output tile cols per block
#define RH   8            // halo = max steps per round
#define RLW  132          // SoA row stride dwords: s0'[33] s1[32] s2[32] s3'[33] +2 pad
#define PR   66           // phys rows: logical -1..64
#define BUFSZ (PR * RLW)  // 8712 dwords per buffer

__device__ __forceinline__ float mapf(float g) {
    float t = 3.9f * g;
    return t - t * g;     // R*g*(1-g)
}

// SoA col mapping (buffer cols -1..128):
//   col 4j+0 -> off j ; col 4j+1 -> off 33+j ; col 4j+2 -> off 65+j ;
//   col 4j+3 -> off 98+j ; left-ext col -1 -> off 97 ; right-ext col 128 -> off 32.
// Per-lane base includes pj; window col literals {97,0,33,65,98,1}.
// Horizontal 6-window read: pairs {97,98},{0,1},{33,65} -> 3 ds_read2_b32.
#define RDROW(P, M) do {                    \
    const float* _p = (P);                  \
    (M)[0] = _p[97]; (M)[5] = _p[1];        \
    (M)[1] = _p[0];  (M)[4] = _p[98];       \
    (M)[2] = _p[33]; (M)[3] = _p[65];       \
} while (0)

// One temporal round: init M=map(src), run `steps` CML steps, store grid to
// dst (clipped if do_clip).
// Structure: each thread's 4x4 patch lives in REGISTERS (st[16]) across
// steps; LDS is only the halo-exchange medium. Per step each thread reads
// just the 20-cell halo ring (10 ds_read2: top 3, bottom 3, left 2, right 2)
// instead of the full 36-dword window, and writes its 16 cells to the OTHER
// buffer (double-buffered -> WAR barrier eliminated, ONE barrier/step).
// The never-written ring of nxt is covered by the shrinking-cone argument:
// garbage at distance >=9 from the valid interior travels 1 cell/step and
// cannot reach the stored region within 8 steps.
__global__ __launch_bounds__(512) void cml_round(
    const float* __restrict__ src,
    const float* __restrict__ drv,
    const float* __restrict__ Kw,
    float* __restrict__ dst,
    int steps, int do_clip)
{
    __shared__ float Bd[2 * BUFSZ];    // 68.1 KiB -> 2 blocks/CU

    const int tid = threadIdx.x;
    const int bid = blockIdx.x;
    const int bc  = bid / 55;               // image*channel index
    const int tl  = bid % 55;               // 11 row-strips x 5 col-tiles
    const int gy0 = (tl / 5) * TR - RH;     // logical buffer row 0 -> gy0
    const int gx0 = (tl % 5) * TC - RH;     // multiple of 4
    const float* __restrict__ simg = src + (size_t)bc * (IMG*IMG);
    const float* __restrict__ dimg = drv + (size_t)bc * (IMG*IMG);
    float*       __restrict__ oimg = dst + (size_t)bc * (IMG*IMG);

    // Folded 3x3 kernel: K' = (0.85*0.3)*K + (0.85*0.7)*delta_center (uniform)
    float kk[9];
    {
        const float c2 = 0.85f * 0.3f;
        const float* kp = Kw + (bc & 3) * 9;
#pragma unroll
        for (int q = 0; q < 9; q++) kk[q] = c2 * kp[q];
        kk[4] += 0.85f * 0.7f;
    }

    const int pj  = tid & 31;               // col patch: owned cols 4pj..4pj+3
    const int pi  = tid >> 5;               // row band:  owned rows 4pi..4pi+3
    const int y0  = pi * 4;
    const int gxb = gx0 + pj * 4;           // global col of owned float4
    const float fxc = ((unsigned)gxb < IMG) ? 1.0f : 0.0f;

    // per-row combined boundary flags, hoisted
    float ffr[4];
#pragma unroll
    for (int rr = 0; rr < 4; rr++)
        ffr[rr] = (((unsigned)(gy0 + y0 + rr) < IMG) ? 1.0f : 0.0f) * fxc;

    // beta*drive for owned cells, hoisted
    float dvs[16];
#pragma unroll
    for (int rr = 0; rr < 4; rr++) {
        const int gy = gy0 + y0 + rr;
        float4 dv = make_float4(0.f, 0.f, 0.f, 0.f);
        if ((unsigned)gy < IMG && (unsigned)gxb < IMG)
            dv = *(const float4*)(dimg + gy*IMG + gxb);
        dvs[rr*4+0] = 0.15f * dv.x;
        dvs[rr*4+1] = 0.15f * dv.y;
        dvs[rr*4+2] = 0.15f * dv.z;
        dvs[rr*4+3] = 0.15f * dv.w;
    }

    // Init: buffer 0 = map(src) over phys rows 0..65, SoA layout.
    for (int u = tid; u < PR * 32; u += 512) {
        const int r = u >> 5;
        const int p = u & 31;
        const int gy  = gy0 + r - 1;
        const int gxq = gx0 + p * 4;
        const bool rowok = (unsigned)gy < IMG;
        float4 v = make_float4(0.f, 0.f, 0.f, 0.f);
        if (rowok && (unsigned)gxq < IMG)
            v = *(const float4*)(simg + gy*IMG + gxq);   // gxq<=508: no row cross
        float* row = Bd + r * RLW;
        row[p]      = mapf(v.x);
        row[33 + p] = mapf(v.y);
        row[65 + p] = mapf(v.z);
        row[98 + p] = mapf(v.w);
        if (p == 0) {                        // left-ext col -1 -> off 97
            float e = (rowok && (unsigned)(gx0 - 1) < IMG)
                    ? simg[gy*IMG + gx0 - 1] : 0.f;
            row[97] = mapf(e);
        }
        if (p == 31) {                       // right-ext col 128 -> off 32
            float e = (rowok && (unsigned)(gx0 + 128) < IMG)
                    ? simg[gy*IMG + gx0 + 128] : 0.f;
            row[32] = mapf(e);
        }
    }
    __syncthreads();

    // Own patch M_1 -> registers (8 ds_read2, vertical pairs)
    float st[16];
    {
        const float* q1 = Bd + (y0 + 1) * RLW + pj;    // rows r0, r0+1
        const float* q3 = q1 + 2 * RLW;                // rows r0+2, r0+3
        st[0]  = q1[0];        st[4]  = q1[RLW];
        st[1]  = q1[33];       st[5]  = q1[33 + RLW];
        st[2]  = q1[65];       st[6]  = q1[65 + RLW];
        st[3]  = q1[98];       st[7]  = q1[98 + RLW];
        st[8]  = q3[0];        st[12] = q3[RLW];
        st[9]  = q3[33];       st[13] = q3[33 + RLW];
        st[10] = q3[65];       st[14] = q3[65 + RLW];
        st[11] = q3[98];       st[15] = q3[98 + RLW];
    }

    float* cur = Bd;
    float* nxt = Bd + BUFSZ;

#pragma unroll 1
    for (int step = 0; step < steps - 1; step++) {
        // ---- halo ring from cur: 10 ds_read2 = 20 dwords ----
        const float* p0 = cur + y0 * RLW + pj;   // phys y0 = logical r0-1
        const float* p5 = p0 + 5 * RLW;          // logical r0+4
        const float* p1 = p0 + RLW;              // rows r0, r0+1
        const float* p3 = p0 + 3 * RLW;          // rows r0+2, r0+3
        float top[6], bot[6], lef[4], rig[4];
        RDROW(p0, top);
        RDROW(p5, bot);
        lef[0] = p1[97];  lef[1] = p1[97 + RLW];
        lef[2] = p3[97];  lef[3] = p3[97 + RLW];
        rig[0] = p1[1];   rig[1] = p1[1 + RLW];
        rig[2] = p3[1];   rig[3] = p3[1 + RLW];

        // ---- rolling 3-row window; commit new st[rr] after b captured it ----
        float a[6], b[6], c[6];
#pragma unroll
        for (int q = 0; q < 6; q++) a[q] = top[q];
        b[0] = lef[0]; b[1] = st[0]; b[2] = st[1];
        b[3] = st[2];  b[4] = st[3]; b[5] = rig[0];
#pragma unroll
        for (int rr = 0; rr < 4; rr++) {
            if (rr < 3) {
                c[0] = lef[rr+1];
                c[1] = st[(rr+1)*4+0]; c[2] = st[(rr+1)*4+1];
                c[3] = st[(rr+1)*4+2]; c[4] = st[(rr+1)*4+3];
                c[5] = rig[rr+1];
            } else {
#pragma unroll
                for (int q = 0; q < 6; q++) c[q] = bot[q];
            }
            const float ff = ffr[rr];
            float ns[4];
#pragma unroll
            for (int k = 0; k < 4; k++) {
                float s = dvs[rr*4+k];
                s += kk[0]*a[k] + kk[1]*a[k+1] + kk[2]*a[k+2];
                s += kk[3]*b[k] + kk[4]*b[k+1] + kk[5]*b[k+2];
                s += kk[6]*c[k] + kk[7]*c[k+1] + kk[8]*c[k+2];
                const float t = 3.9f * s;
                ns[k] = (t - t*s) * ff;
            }
#pragma unroll
            for (int q = 0; q < 6; q++) { a[q] = b[q]; b[q] = c[q]; }
#pragma unroll
            for (int k = 0; k < 4; k++) st[rr*4+k] = ns[k];   // old row rr now in a
        }

        // ---- write own patch to nxt: 8 ds_write2 = 16 dwords ----
        {
            float* w1 = nxt + (y0 + 1) * RLW + pj;
            float* w3 = w1 + 2 * RLW;
            w1[0]  = st[0];   w1[RLW]      = st[4];
            w1[33] = st[1];   w1[33 + RLW] = st[5];
            w1[65] = st[2];   w1[65 + RLW] = st[6];
            w1[98] = st[3];   w1[98 + RLW] = st[7];
            w3[0]  = st[8];   w3[RLW]      = st[12];
            w3[33] = st[9];   w3[33 + RLW] = st[13];
            w3[65] = st[10];  w3[65 + RLW] = st[14];
            w3[98] = st[11];  w3[98 + RLW] = st[15];
        }
        __syncthreads();   // nxt complete before anyone reads it (single barrier)
        float* tmp = cur; cur = nxt; nxt = tmp;
    }

    // ---- final step: compute grid (no map/flag), store valid interior ----
    {
        const float* p0 = cur + y0 * RLW + pj;
        const float* p5 = p0 + 5 * RLW;
        const float* p1 = p0 + RLW;
        const float* p3 = p0 + 3 * RLW;
        float top[6], bot[6], lef[4], rig[4];
        RDROW(p0, top);
        RDROW(p5, bot);
        lef[0] = p1[97];  lef[1] = p1[97 + RLW];
        lef[2] = p3[97];  lef[3] = p3[97 + RLW];
        rig[0] = p1[1];   rig[1] = p1[1 + RLW];
        rig[2] = p3[1];   rig[3] = p3[1 + RLW];

        float a[6], b[6], c[6];
#pragma unroll
        for (int q = 0; q < 6; q++) a[q] = top[q];
        b[0] = lef[0]; b[1] = st[0]; b[2] = st[1];
        b[3] = st[2];  b[4] = st[3]; b[5] = rig[0];
#pragma unroll
        for (int rr = 0; rr < 4; rr++) {
            if (rr < 3) {
                c[0] = lef[rr+1];
                c[1] = st[(rr+1)*4+0]; c[2] = st[(rr+1)*4+1];
                c[3] = st[(rr+1)*4+2]; c[4] = st[(rr+1)*4+3];
                c[5] = rig[rr+1];
            } else {
#pragma unroll
                for (int q = 0; q < 6; q++) c[q] = bot[q];
            }
            float ns[4];
#pragma unroll
            for (int k = 0; k < 4; k++) {
                float s = dvs[rr*4+k];
                s += kk[0]*a[k] + kk[1]*a[k+1] + kk[2]*a[k+2];
                s += kk[3]*b[k] + kk[4]*b[k+1] + kk[5]*b[k+2];
                s += kk[6]*c[k] + kk[7]*c[k+1] + kk[8]*c[k+2];
                ns[k] = s;
            }
#pragma unroll
            for (int q = 0; q < 6; q++) { a[q] = b[q]; b[q] = c[q]; }
#pragma unroll
            for (int k = 0; k < 4; k++) st[rr*4+k] = ns[k];
        }
    }
    // Valid region: rows [8,56) -> pi in [2,13]; cols [8,120) -> pj in [2,29].
    if (pi >= 2 && pi <= 13 && pj >= 2 && pj <= 29) {
#pragma unroll
        for (int rr = 0; rr < 4; rr++) {
            const int gy = gy0 + y0 + rr;       // >= 0 (pi>=2)
            if (gy < IMG && gxb + 3 < IMG) {
                float4 v = make_float4(st[rr*4+0], st[rr*4+1],
                                       st[rr*4+2], st[rr*4+3]);
                if (do_clip) {
                    v.x = fminf(fmaxf(v.x, 1e-4f), 1.0f - 1e-4f);
                    v.y = fminf(fmaxf(v.y, 1e-4f), 1.0f - 1e-4f);
                    v.z = fminf(fmaxf(v.z, 1e-4f), 1.0f - 1e-4f);
                    v.w = fminf(fmaxf(v.w, 1e-4f), 1.0f - 1e-4f);
                }
                *(float4*)(oimg + gy*IMG + gxb) = v;
            }
        }
    }
}

// ---------------- Fallback: single-kernel 15-step version (Round-4) ----------
#define TILE  128
#define OFF_Y 16
#define OFF_X 18
#define BUFY  160
#define BUFX  164
#define LW    172
#define NP    1014

__device__ __forceinline__ void read_row6(const float* __restrict__ p, int xw,
                                          float* m) {
    const float4 mid = *(const float4*)(p + xw + 4);
    m[0] = p[xw + 3];
    m[1] = mid.x; m[2] = mid.y; m[3] = mid.z; m[4] = mid.w;
    m[5] = p[xw + 8];
}

__global__ __launch_bounds__(1024, 4) void cml_fused(
    const float* __restrict__ drive,
    const float* __restrict__ Kw,
    float* __restrict__ out)
{
    __shared__ float lds[BUFY * LW];
    const int tid = threadIdx.x;
    const int bid = blockIdx.x;
    const int bc  = bid >> 4;
    const int tl  = bid & 15;
    const int gy0 = (tl >> 2) * TILE - OFF_Y;
    const int gx0 = (tl & 3)  * TILE - OFF_X;
    const float* __restrict__ img  = drive + (size_t)bc * (IMG*IMG);
    float*       __restrict__ oimg = out   + (size_t)bc * (IMG*IMG);
    float kk[9];
    {
        const float c2 = 0.85f * 0.3f;
        const float* kp = Kw + (bc & 3) * 9;
#pragma unroll
        for (int q = 0; q < 9; q++) kk[q] = c2 * kp[q];
        kk[4] += 0.85f * 0.7f;
    }
    const int t2 = tid < NP ? tid : NP - 1;
    const int pi = t2 / 39;
    const int pj = t2 - pi * 39;
    const int y0 = 2 + 6 * pi;
    const int xw = 4 * pj;
    float dvs[24], fx[4], fy[6];
#pragma unroll
    for (int k = 0; k < 4; k++)
        fx[k] = ((unsigned)(gx0 + xw + 4 + k) < IMG) ? 1.0f : 0.0f;
#pragma unroll
    for (int rr = 0; rr < 6; rr++) {
        const int gy = gy0 + y0 + rr;
        fy[rr] = ((unsigned)gy < IMG) ? 1.0f : 0.0f;
#pragma unroll
        for (int k = 0; k < 4; k++) {
            const int gx = gx0 + xw + 4 + k;
            dvs[rr*4+k] = (((unsigned)gy < IMG) && ((unsigned)gx < IMG))
                        ? 0.15f * img[gy*IMG + gx] : 0.0f;
        }
    }
    for (int u = tid; u < BUFY * (LW/2); u += 1024) {
        const int yy = u / (LW/2);
        const int xx = (u - yy * (LW/2)) * 2;
        const int gy = gy0 + yy;
        const int gxb = gx0 + xx;
        float2 v = make_float2(0.f, 0.f);
        if (xx < BUFX && (unsigned)gy < IMG && (unsigned)gxb < IMG)
            v = *(const float2*)(img + gy*IMG + gxb);
        v.x = mapf(v.x); v.y = mapf(v.y);
        *(float2*)(lds + yy*LW + xx) = v;
    }
    __syncthreads();
    float st[24];
#pragma unroll 1
    for (int step = 0; step < 14; step++) {
        {
            float a[6], b[6], c[6];
            const float* p = lds + (y0 - 1) * LW;
            read_row6(p, xw, a);  p += LW;
            read_row6(p, xw, b);
#pragma unroll
            for (int rr = 0; rr < 6; rr++) {
                p += LW;
                read_row6(p, xw, c);
                const float fyr = fy[rr];
#pragma unroll
                for (int k = 0; k < 4; k++) {
                    float s = dvs[rr*4+k];
                    s += kk[0]*a[k] + kk[1]*a[k+1] + kk[2]*a[k+2];
                    s += kk[3]*b[k] + kk[4]*b[k+1] + kk[5]*b[k+2];
                    s += kk[6]*c[k] + kk[7]*c[k+1] + kk[8]*c[k+2];
                    const float t = 3.9f * s;
                    st[rr*4+k] = (t - t*s) * fyr * fx[k];
                }
#pragma unroll
                for (int q = 0; q < 6; q++) { a[q] = b[q]; b[q] = c[q]; }
            }
        }
        __syncthreads();
        {
            float* w = lds + y0 * LW + xw + 4;
#pragma unroll
            for (int rr = 0; rr < 6; rr++) {
                *(float4*)w = make_float4(st[rr*4+0], st[rr*4+1],
                                          st[rr*4+2], st[rr*4+3]);
                w += LW;
            }
        }
        __syncthreads();
    }
    {
        float a[6], b[6], c[6];
        const float* p = lds + (y0 - 1) * LW;
        read_row6(p, xw, a);  p += LW;
        read_row6(p, xw, b);
#pragma unroll
        for (int rr = 0; rr < 6; rr++) {
            p += LW;
            read_row6(p, xw, c);
#pragma unroll
            for (int k = 0; k < 4; k++) {
                float s = dvs[rr*4+k];
                s += kk[0]*a[k] + kk[1]*a[k+1] + kk[2]*a[k+2];
                s += kk[3]*b[k] + kk[4]*b[k+1] + kk[5]*b[k+2];
                s += kk[6]*c[k] + kk[7]*c[k+1] + kk[8]*c[k+2];
                st[rr*4+k] = fminf(fmaxf(s, 1e-4f), 1.0f - 1e-4f);
            }
#pragma unroll
            for (int q = 0; q < 6; q++) { a[q] = b[q]; b[q] = c[q]; }
        }
    }
#pragma unroll
    for (int rr = 0; rr < 6; rr++) {
        const int r = y0 + rr;
        if (r >= OFF_Y && r < OFF_Y + TILE) {
#pragma unroll
            for (int h = 0; h < 2; h++) {
                const int col = xw + 4 + 2*h;
                if (col >= OFF_X && col + 1 < OFF_X + TILE) {
                    *(float2*)(oimg + (size_t)(gy0 + r) * IMG + (gx0 + col)) =
                        make_float2(st[rr*4 + 2*h], st[rr*4 + 2*h + 1]);
                }
            }
        }
    }
}

extern "C" void kernel_launch(void* const* d_in, const int* in_sizes, int n_in,
                              void* d_out, int out_size, void* d_ws, size_t ws_size,
                              hipStream_t stream)
{
    const float* drive = (const float*)d_in[0];
    const float* Kw    = (const float*)d_in[1];
    float* out         = (float*)d_out;
    const size_t need  = (size_t)256 * IMG * IMG * sizeof(float);  // 256 MiB

    if (ws_size >= need) {
        float* g8 = (float*)d_ws;
        // 256 images x 55 tiles (11 row-strips x 5 col-tiles) = 14080 blocks
        cml_round<<<dim3(14080), dim3(512), 0, stream>>>(drive, drive, Kw, g8, 8, 0);
        cml_round<<<dim3(14080), dim3(512), 0, stream>>>(g8, drive, Kw, out, 7, 1);
    } else {
        cml_fused<<<dim3(4096), dim3(1024), 0, stream>>>(drive, Kw, out);
    }
}